// Round 12
// baseline (242.615 us; speedup 1.0000x reference)
//
#include <hip/hip_runtime.h>
#include <hip/hip_bf16.h>
#include <stdint.h>

// B=8, C=256, HW=16384, HEADS=4, HEAD_DIM=64, SCALE=1/8.
// G[b]=x x^T (split-bf16 MFMA, in-register hi/lo split of fp32 x);
// T = Wq G; logits = T Wk^T (+bias); attn = softmax;
// M = Wproj blockdiag(attn); P = M Wv; out = P x + (M bv + bproj).

#define HW 16384
#define SCALE_F 0.125f
#define NF 16384.0f
#define NKC 64          // K-chunks for gram split-K (chunk = 256)

typedef __attribute__((ext_vector_type(8))) short bf16x8;
typedef __attribute__((ext_vector_type(4))) float f32x4;

__device__ __forceinline__ unsigned short f2bf(float f) {
    union { float f; uint32_t u; } v; v.f = f;
    uint32_t u = v.u;
    return (unsigned short)((u + 0x7fffu + ((u >> 16) & 1u)) >> 16);  // RNE
}
__device__ __forceinline__ float bf2f(unsigned short s) {
    union { uint32_t u; float f; } v; v.u = ((uint32_t)s) << 16;
    return v.f;
}
// packed f32x2 -> bf16x2 (RNE, hardware v_cvt_pk_bf16_f32); low16 = a, high16 = b
__device__ __forceinline__ uint32_t pk_bf16(float a, float b) {
    __hip_bfloat162 h = __float22bfloat162_rn(make_float2(a, b));
    union { __hip_bfloat162 h; uint32_t u; } c; c.h = h; return c.u;
}
__device__ __forceinline__ float ubf2f(uint32_t hibits) {   // bf16 bits already in [31:16]
    union { uint32_t u; float f; } v; v.u = hibits; return v.f;
}

// ---------------- K1: Gram; one 256x256 tile per (kc,b), K-chunk = 256 (8 steps),
// 512 blocks -> 2 blocks/CU for TLP across barrier drains. cvt_pk staging.
__global__ __launch_bounds__(512) void gram(
        const float* __restrict__ x, float* __restrict__ partG,
        float* __restrict__ parts_s) {
    const int kc = blockIdx.x;    // 0..63, K-chunk of 256
    const int b  = blockIdx.y;
    __shared__ __align__(16) unsigned short Hs[2][256 * 32];
    __shared__ __align__(16) unsigned short Ls[2][256 * 32];
    const int tid = threadIdx.x, lane = tid & 63, w = tid >> 6;
    const int l15 = lane & 15, lg = lane >> 4;
    const int wr = w >> 1, wc = w & 1;          // 4x64-row x 2x128-col wave grid
    const int srow = tid >> 1, shalf = tid & 1; // staging: row, 16-col half
    const int m4 = (srow >> 1) & 3;             // swizzle key for this row
    const float* xb = x + (size_t)b * 256 * HW + (size_t)srow * HW + kc * 256 + shalf * 16;
    f32x4 acc[4][8] = {};
    float rs = 0.f;
    float4 ld[4];

#define LOADR(kstep)                                                            \
    {                                                                           \
        const float4* src = reinterpret_cast<const float4*>(xb + (kstep) * 32); \
        ld[0] = src[0]; ld[1] = src[1]; ld[2] = src[2]; ld[3] = src[3];         \
    }
#define STORE(sel)                                                              \
    {                                                                           \
        _Pragma("unroll")                                                       \
        for (int cq = 0; cq < 2; ++cq) {                                        \
            const float vv[8] = {ld[2*cq].x, ld[2*cq].y, ld[2*cq].z, ld[2*cq].w,\
                                 ld[2*cq+1].x, ld[2*cq+1].y, ld[2*cq+1].z, ld[2*cq+1].w}; \
            uint4 Hv, Lv;                                                       \
            uint32_t* Hp = reinterpret_cast<uint32_t*>(&Hv);                    \
            uint32_t* Lp = reinterpret_cast<uint32_t*>(&Lv);                    \
            _Pragma("unroll")                                                   \
            for (int p = 0; p < 4; ++p) {                                       \
                const float a0 = vv[2*p], a1 = vv[2*p+1];                       \
                const uint32_t hp = pk_bf16(a0, a1);                            \
                const float lo0 = a0 - ubf2f(hp << 16);                         \
                const float lo1 = a1 - ubf2f(hp & 0xffff0000u);                 \
                Hp[p] = hp;                                                     \
                Lp[p] = pk_bf16(lo0, lo1);                                      \
                rs += a0 + a1;                                                  \
            }                                                                   \
            const int slot = ((shalf * 2 + cq) ^ m4) << 4;                      \
            *reinterpret_cast<uint4*>((char*)(&Hs[sel][0]) + srow * 64 + slot) = Hv; \
            *reinterpret_cast<uint4*>((char*)(&Ls[sel][0]) + srow * 64 + slot) = Lv; \
        }                                                                       \
    }
#define DO_MFMA(sel)                                                            \
    {                                                                           \
        bf16x8 fah[4], fal[4];                                                  \
        _Pragma("unroll")                                                       \
        for (int i = 0; i < 4; ++i) {                                           \
            const int row = wr * 64 + i * 16 + l15;                             \
            const int off = row * 64 + ((lg ^ ((row >> 1) & 3)) << 4);          \
            fah[i] = *reinterpret_cast<const bf16x8*>((const char*)&Hs[sel][0] + off); \
            fal[i] = *reinterpret_cast<const bf16x8*>((const char*)&Ls[sel][0] + off); \
        }                                                                       \
        _Pragma("unroll")                                                       \
        for (int j = 0; j < 8; ++j) {                                           \
            const int row = wc * 128 + j * 16 + l15;                            \
            const int off = row * 64 + ((lg ^ ((row >> 1) & 3)) << 4);          \
            const bf16x8 fbh = *reinterpret_cast<const bf16x8*>((const char*)&Hs[sel][0] + off); \
            const bf16x8 fbl = *reinterpret_cast<const bf16x8*>((const char*)&Ls[sel][0] + off); \
            _Pragma("unroll")                                                   \
            for (int i = 0; i < 4; ++i) {                                       \
                acc[i][j] = __builtin_amdgcn_mfma_f32_16x16x32_bf16(fah[i], fbh, acc[i][j], 0, 0, 0); \
                acc[i][j] = __builtin_amdgcn_mfma_f32_16x16x32_bf16(fah[i], fbl, acc[i][j], 0, 0, 0); \
                acc[i][j] = __builtin_amdgcn_mfma_f32_16x16x32_bf16(fal[i], fbh, acc[i][j], 0, 0, 0); \
            }                                                                   \
        }                                                                       \
    }

    LOADR(0);
    STORE(0);
    __syncthreads();
    for (int t = 0; t < 8; ++t) {
        if (t < 7) LOADR(t + 1);
        DO_MFMA(t & 1);
        if (t < 7) STORE((t + 1) & 1);
        __syncthreads();
    }
#undef LOADR
#undef STORE
#undef DO_MFMA

    // row-sum partials: threads 2r,2r+1 share row r
    rs += __shfl_xor(rs, 1);
    if ((tid & 1) == 0) parts_s[(size_t)(b * NKC + kc) * 256 + srow] = rs;

    float* pw = partG + (size_t)(b * NKC + kc) * 65536;
    #pragma unroll
    for (int i = 0; i < 4; ++i)
        #pragma unroll
        for (int rr = 0; rr < 4; ++rr) {
            const int m = wr * 64 + i * 16 + lg * 4 + rr;
            #pragma unroll
            for (int j = 0; j < 8; ++j)
                pw[m * 256 + wc * 128 + j * 16 + l15] = acc[i][j][rr];
        }
}

// ---------------- K2: G = sum over NKC chunks of partG (float4 vectorized)
__global__ __launch_bounds__(256) void greduce(
        const float4* __restrict__ partG4, float4* __restrict__ G4) {
    const int g = blockIdx.x * 256 + threadIdx.x;   // 131072 float4s
    const int b = g >> 14, i4 = g & 16383;
    float4 a = make_float4(0.f, 0.f, 0.f, 0.f);
    #pragma unroll 8
    for (int kc = 0; kc < NKC; ++kc) {
        const float4 v = partG4[(size_t)(b * NKC + kc) * 16384 + i4];
        a.x += v.x; a.y += v.y; a.z += v.z; a.w += v.w;
    }
    G4[g] = a;
}

// ---------------- K3: fused tgemm + logits + softmax (+ s-reduce) per (b,h)
__global__ __launch_bounds__(512) void tlogits(
        const float* __restrict__ G, const float* __restrict__ Wqkv,
        const float* __restrict__ bqkv, const float* __restrict__ parts_s,
        float* __restrict__ attn) {
    const int bh = blockIdx.x, b = bh >> 2, h = bh & 3;
    const int tid = threadIdx.x;
    __shared__ __align__(16) float SM[38528];     // 154 KB
    float* R1 = SM;            // [64][264]: G chunk, then T
    float* R2 = SM + 16896;    // [256][66]: Wk^T
    float* WQ = SM + 33792;    // [64][68]: Wq chunk; later lgs [64][65]
    float* SB = SM + 38144;    // 256
    float* QS = SM + 38400;    // 64
    float* KS = SM + 38464;    // 64
    const float* Gb = G + (size_t)b * 65536;
    const float* Wq = Wqkv + (size_t)(h * 64) * 256;
    const float* Wk = Wqkv + (size_t)(256 + h * 64) * 256;

    if (tid < 256) {   // SB = s_b (reduce parts)
        float a = 0.f;
        #pragma unroll 8
        for (int kc = 0; kc < NKC; ++kc)
            a += parts_s[(size_t)(b * NKC + kc) * 256 + tid];
        SB[tid] = a;
    }
    {   // stage Wk^T -> R2
        const int e = tid >> 3, cq = (tid & 7) * 32;
        #pragma unroll
        for (int q = 0; q < 8; ++q) {
            const float4 w4 = *reinterpret_cast<const float4*>(Wk + (size_t)e * 256 + cq + q * 4);
            R2[(cq + q * 4 + 0) * 66 + e] = w4.x;
            R2[(cq + q * 4 + 1) * 66 + e] = w4.y;
            R2[(cq + q * 4 + 2) * 66 + e] = w4.z;
            R2[(cq + q * 4 + 3) * 66 + e] = w4.w;
        }
    }
    __syncthreads();
    if (tid < 64) {   // ks = Wk s_b
        float a = 0.f;
        for (int c = 0; c < 256; ++c) a += R2[c * 66 + tid] * SB[c];
        KS[tid] = a;
    }

    // phase A: T[d][c'] = sum_c Wq[d][c] G[c][c']; thread owns d=dq*4+i, c'=cb+32*jj
    const int dq = tid >> 5, cb = tid & 31;
    float tacc[4][8] = {};
    float qacc = 0.f;
    for (int cc = 0; cc < 4; ++cc) {
        {   // stage G rows [cc*64,+64) -> R1
            const int r = tid >> 3, cq = (tid & 7) * 32;
            #pragma unroll
            for (int q = 0; q < 8; ++q)
                *reinterpret_cast<float4*>(&R1[r * 264 + cq + q * 4]) =
                    *reinterpret_cast<const float4*>(Gb + (size_t)(cc * 64 + r) * 256 + cq + q * 4);
        }
        {   // stage Wq chunk cols -> WQ
            const int r = tid >> 3, c8 = (tid & 7) * 8;
            *reinterpret_cast<float4*>(&WQ[r * 68 + c8]) =
                *reinterpret_cast<const float4*>(Wq + (size_t)r * 256 + cc * 64 + c8);
            *reinterpret_cast<float4*>(&WQ[r * 68 + c8 + 4]) =
                *reinterpret_cast<const float4*>(Wq + (size_t)r * 256 + cc * 64 + c8 + 4);
        }
        __syncthreads();
        for (int c = 0; c < 64; ++c) {
            float wv[4];
            #pragma unroll
            for (int i = 0; i < 4; ++i) wv[i] = WQ[(dq * 4 + i) * 68 + c];
            #pragma unroll
            for (int jj = 0; jj < 8; ++jj) {
                const float gv = R1[c * 264 + cb + 32 * jj];
                #pragma unroll
                for (int i = 0; i < 4; ++i) tacc[i][jj] += wv[i] * gv;
            }
        }
        if (tid < 64) {   // qs partial on this Wq chunk
            float a = 0.f;
            for (int c = 0; c < 64; ++c) a += WQ[tid * 68 + c] * SB[cc * 64 + c];
            qacc += a;
        }
        __syncthreads();
    }
    if (tid < 64) QS[tid] = qacc;
    #pragma unroll
    for (int i = 0; i < 4; ++i)
        #pragma unroll
        for (int jj = 0; jj < 8; ++jj)
            R1[(dq * 4 + i) * 264 + cb + 32 * jj] = tacc[i][jj];   // T -> R1
    __syncthreads();

    // phase B: logits[d][e] = sum_c' T[d][c'] Wk[e][c']
    const int e2 = tid & 31;
    float lacc[4][2] = {};
    for (int c = 0; c < 256; ++c) {
        float tv[4];
        #pragma unroll
        for (int i = 0; i < 4; ++i) tv[i] = R1[(dq * 4 + i) * 264 + c];
        #pragma unroll
        for (int k = 0; k < 2; ++k) {
            const float wv = R2[c * 66 + e2 * 2 + k];
            #pragma unroll
            for (int i = 0; i < 4; ++i) lacc[i][k] += tv[i] * wv;
        }
    }
    float* lgs = WQ;   // reuse as [64][65]
    const float* bq = bqkv + h * 64;
    const float* bk = bqkv + 256 + h * 64;
    #pragma unroll
    for (int i = 0; i < 4; ++i) {
        const int d = dq * 4 + i;
        #pragma unroll
        for (int k = 0; k < 2; ++k) {
            const int e = e2 * 2 + k;
            lgs[d * 65 + e] = SCALE_F * (lacc[i][k] + bq[d] * KS[e] + bk[e] * QS[d] + NF * bq[d] * bk[e]);
        }
    }
    __syncthreads();
    if (tid < 64) {
        float m = -1e30f;
        for (int e = 0; e < 64; ++e) m = fmaxf(m, lgs[tid * 65 + e]);
        float sum = 0.f;
        for (int e = 0; e < 64; ++e) {
            const float ex = __expf(lgs[tid * 65 + e] - m);
            sum += ex;
            lgs[tid * 65 + e] = ex;
        }
        const float inv = 1.f / sum;
        float* ar = attn + ((size_t)bh * 64 + tid) * 64;
        for (int e = 0; e < 64; ++e) ar[e] = lgs[tid * 65 + e] * inv;
    }
}

// ---------------- K4: fused build_M + build_P + cvec; block = (b, 16-o slice)
__global__ __launch_bounds__(256) void buildMP(
        const float* __restrict__ attn, const float* __restrict__ Wproj,
        const float* __restrict__ Wqkv, const float* __restrict__ bqkv,
        const float* __restrict__ bproj, unsigned short* __restrict__ P,
        float* __restrict__ cvec) {
    const int blk = blockIdx.x;          // 128 = 8 b x 16 slices
    const int b = blk >> 4, o0 = (blk & 15) * 16;
    const int tid = threadIdx.x;
    __shared__ __align__(16) float U[16512];    // attn[b] (16384) then Wv chunk [64][258]
    __shared__ __align__(16) float WpL[16 * 258];
    __shared__ __align__(16) float ML[16 * 258];
    const int og = tid >> 6, cb = tid & 63;     // o = o0+og*4+i, he/c = j*64+cb

    {   // stage attn[b]
        const float* ab = attn + (size_t)b * 16384;
        #pragma unroll
        for (int q = 0; q < 16; ++q)
            *reinterpret_cast<float4*>(&U[tid * 64 + q * 4]) =
                *reinterpret_cast<const float4*>(ab + tid * 64 + q * 4);
    }
    {   // stage Wproj slice [16][256]
        const int r = tid >> 4, cc = (tid & 15) * 16;
        #pragma unroll
        for (int q = 0; q < 4; ++q)
            *reinterpret_cast<float4*>(&WpL[r * 258 + cc + q * 4]) =
                *reinterpret_cast<const float4*>(Wproj + (size_t)(o0 + r) * 256 + cc + q * 4);
    }
    __syncthreads();

    // phase 1: M[o][j*64+cb] = sum_d Wp[o][j*64+d] * att[j][d][cb]
    float macc[4][4] = {};
    #pragma unroll
    for (int j = 0; j < 4; ++j)
        for (int d = 0; d < 64; ++d) {
            const float a = U[j * 4096 + d * 64 + cb];
            #pragma unroll
            for (int i = 0; i < 4; ++i)
                macc[i][j] += WpL[(og * 4 + i) * 258 + j * 64 + d] * a;
        }
    #pragma unroll
    for (int i = 0; i < 4; ++i)
        #pragma unroll
        for (int j = 0; j < 4; ++j)
            ML[(og * 4 + i) * 258 + j * 64 + cb] = macc[i][j];
    __syncthreads();

    if (tid < 16) {   // cvec
        const int o = o0 + tid;
        float a = bproj[o];
        for (int he = 0; he < 256; ++he) a += ML[tid * 258 + he] * bqkv[512 + he];
        cvec[b * 256 + o] = a;
    }

    // phase 2: P[o][j*64+cb] = sum_he M[o][he] * Wv[he][j*64+cb]
    float pacc[4][4] = {};
    for (int ch = 0; ch < 4; ++ch) {
        {   // stage Wv chunk rows [ch*64,+64) into U [64][258]
            const int r = tid >> 2, cc = (tid & 3) * 64;
            #pragma unroll
            for (int q = 0; q < 16; ++q)
                *reinterpret_cast<float4*>(&U[r * 258 + cc + q * 4]) =
                    *reinterpret_cast<const float4*>(Wqkv + (size_t)(512 + ch * 64 + r) * 256 + cc + q * 4);
        }
        __syncthreads();
        for (int he = 0; he < 64; ++he) {
            float mw[4];
            #pragma unroll
            for (int i = 0; i < 4; ++i) mw[i] = ML[(og * 4 + i) * 258 + ch * 64 + he];
            #pragma unroll
            for (int j = 0; j < 4; ++j) {
                const float wv = U[he * 258 + j * 64 + cb];
                #pragma unroll
                for (int i = 0; i < 4; ++i) pacc[i][j] += mw[i] * wv;
            }
        }
        __syncthreads();
    }
    unsigned short* Pb = P + (size_t)b * 65536;
    #pragma unroll
    for (int i = 0; i < 4; ++i)
        #pragma unroll
        for (int j = 0; j < 4; ++j)
            Pb[(size_t)(o0 + og * 4 + i) * 256 + j * 64 + cb] = f2bf(pacc[i][j]);
}

// ---------------- K5: out = P x + cvec. 128-n tile, 64 KB LDS, single barrier.
// ALL 64 x-loads issued upfront, P-fragment 1-step software prefetch.
// Operand-swapped MFMA, float4 stores.
__global__ __launch_bounds__(512) void out_gemm(
        const unsigned short* __restrict__ P, const float* __restrict__ x,
        const float* __restrict__ cvec, float* __restrict__ out) {
    const int n0 = blockIdx.x * 128;
    const int b  = blockIdx.y;
    __shared__ __align__(16) unsigned short Bs[8 * 128 * 32];  // 64 KB: [s][n][32k] swizzled
    const int tid = threadIdx.x, lane = tid & 63, w = tid >> 6;
    const int wr = w >> 1, wc = w & 1;          // 4x64(m) x 2x64(n) wave grid
    const int l15 = lane & 15, lg = lane >> 4;
    const unsigned short* Pb = P + (size_t)b * 65536;

    // ---- stage: issue ALL loads, then convert+store (single latency exposure)
    {
        const int sn = tid & 127;                  // n row
        const int sg = tid >> 7;                   // k-slot 0..3 (8 k each)
        const float* xcol = x + (size_t)b * 256 * HW + n0 + sn;
        float bv[64];
        #pragma unroll
        for (int s = 0; s < 8; ++s)
            #pragma unroll
            for (int i = 0; i < 8; ++i)
                bv[s * 8 + i] = xcol[(size_t)(s * 32 + sg * 8 + i) * HW];
        const int wslot = ((sg ^ ((sn >> 1) & 3)) << 4);
        #pragma unroll
        for (int s = 0; s < 8; ++s) {
            uint4 Bv;
            uint32_t* Bp = reinterpret_cast<uint32_t*>(&Bv);
            #pragma unroll
            for (int p = 0; p < 4; ++p)
                Bp[p] = pk_bf16(bv[s * 8 + 2 * p], bv[s * 8 + 2 * p + 1]);
            *reinterpret_cast<uint4*>((char*)Bs + s * 8192 + sn * 64 + wslot) = Bv;
        }
    }
    __syncthreads();

    // ---- compute: K=256, P fragments prefetched 1 step ahead (static ping-pong)
    f32x4 acc[4][4] = {};   // [m-frag][n-frag]; lane: m = +l15, n = +lg*4+reg
    const int m4r = (l15 >> 1) & 3;
    bf16x8 fp0[4], fp1[4];
    #pragma unroll
    for (int i = 0; i < 4; ++i)
        fp0[i] = *reinterpret_cast<const bf16x8*>(
            Pb + (size_t)(wr * 64 + i * 16 + l15) * 256 + lg * 8);
    #pragma unroll
    for (int s = 0; s < 8; ++s) {
        bf16x8* cur = (s & 1) ? fp1 : fp0;
        bf16x8* nxt = (s & 1) ? fp0 : fp1;
        if (s < 7) {
            #pragma unroll
            for (int i = 0; i < 4; ++i)
                nxt[i] = *reinterpret_cast<const bf16x8*>(
                    Pb + (size_t)(wr * 64 + i * 16 + l15) * 256 + (s + 1) * 32 + lg * 8);
        }
        #pragma unroll
        for (int j = 0; j < 4; ++j) {
            const int row = wc * 64 + j * 16 + l15;
            const bf16x8 fx = *reinterpret_cast<const bf16x8*>(
                (const char*)Bs + s * 8192 + row * 64 + ((lg ^ m4r) << 4));  // A operand (rows = n)
            #pragma unroll
            for (int i = 0; i < 4; ++i)
                acc[i][j] = __builtin_amdgcn_mfma_f32_16x16x32_bf16(fx, cur[i], acc[i][j], 0, 0, 0);
        }
    }

    float* ob = out + (size_t)b * 256 * HW;
    #pragma unroll
    for (int i = 0; i < 4; ++i) {
        const int m = wr * 64 + i * 16 + l15;
        const float bp = cvec[b * 256 + m];
        #pragma unroll
        for (int j = 0; j < 4; ++j) {
            const int n = n0 + wc * 64 + j * 16 + lg * 4;
            float4 o4;
            o4.x = acc[i][j][0] + bp;
            o4.y = acc[i][j][1] + bp;
            o4.z = acc[i][j][2] + bp;
            o4.w = acc[i][j][3] + bp;
            *reinterpret_cast<float4*>(ob + (size_t)m * HW + n) = o4;
        }
    }
}

extern "C" void kernel_launch(void* const* d_in, const int* in_sizes, int n_in,
                              void* d_out, int out_size, void* d_ws, size_t ws_size,
                              hipStream_t stream) {
    const float* x     = (const float*)d_in[0];
    const float* Wqkv  = (const float*)d_in[1];
    const float* bqkv  = (const float*)d_in[2];
    const float* Wproj = (const float*)d_in[3];
    const float* bproj = (const float*)d_in[4];
    float* out = (float*)d_out;

    // ws layout (bytes):
    //   partG  :         0  134217728   (8*64*256*256 f32)
    //   G      : 134217728    2097152
    //   attn   : 136314880     524288
    //   P      : 136839168    1048576
    //   cvec   : 137887744       8192
    //   partsS : 137895936     524288   (8*64*256 f32) -> ~132 MiB
    char* ws = (char*)d_ws;
    float* partG   = (float*)(ws);
    float* G       = (float*)(ws + 134217728);
    float* attn    = (float*)(ws + 136314880);
    unsigned short* P = (unsigned short*)(ws + 136839168);
    float* cvec    = (float*)(ws + 137887744);
    float* parts_s = (float*)(ws + 137895936);

    gram    <<<dim3(NKC, 8), 512, 0, stream>>>(x, partG, parts_s);
    greduce <<<512,          256, 0, stream>>>((const float4*)partG, (float4*)G);
    tlogits <<<32,           512, 0, stream>>>(G, Wqkv, bqkv, parts_s, attn);
    buildMP <<<128,          256, 0, stream>>>(attn, Wproj, Wqkv, bqkv, bproj, P, cvec);
    out_gemm<<<dim3(128, 8), 512, 0, stream>>>(P, x, cvec, out);
}

// Round 13
// 232.014 us; speedup vs baseline: 1.0457x; 1.0457x over previous
//
#include <hip/hip_runtime.h>
#include <hip/hip_bf16.h>
#include <stdint.h>

// B=8, C=256, HW=16384, HEADS=4, HEAD_DIM=64, SCALE=1/8.
// G[b]=x x^T (split-bf16 MFMA, in-register hi/lo split of fp32 x);
// T = Wq G; logits = T Wk^T (+bias); attn = softmax;
// M = Wproj blockdiag(attn); P = M Wv; out = P x + (M bv + bproj).

#define HW 16384
#define SCALE_F 0.125f
#define NF 16384.0f

typedef __attribute__((ext_vector_type(8))) short bf16x8;
typedef __attribute__((ext_vector_type(4))) float f32x4;

__device__ __forceinline__ unsigned short f2bf(float f) {
    union { float f; uint32_t u; } v; v.f = f;
    uint32_t u = v.u;
    return (unsigned short)((u + 0x7fffu + ((u >> 16) & 1u)) >> 16);  // RNE
}
__device__ __forceinline__ float bf2f(unsigned short s) {
    union { uint32_t u; float f; } v; v.u = ((uint32_t)s) << 16;
    return v.f;
}
// packed f32x2 -> bf16x2 (RNE, hardware v_cvt_pk_bf16_f32); low16 = a, high16 = b
__device__ __forceinline__ uint32_t pk_bf16(float a, float b) {
    __hip_bfloat162 h = __float22bfloat162_rn(make_float2(a, b));
    union { __hip_bfloat162 h; uint32_t u; } c; c.h = h; return c.u;
}
__device__ __forceinline__ float ubf2f(uint32_t hibits) {   // bf16 bits already in [31:16]
    union { uint32_t u; float f; } v; v.u = hibits; return v.f;
}

// ---------------- K1: Gram (R11 config: 32 K-chunks of 512, 256 blocks); cvt_pk staging
__global__ __launch_bounds__(512) void gram(
        const float* __restrict__ x, float* __restrict__ partG,
        float* __restrict__ parts_s) {
    const int kc = blockIdx.x;    // 0..31, K-chunk of 512
    const int b  = blockIdx.y;
    __shared__ __align__(16) unsigned short Hs[2][256 * 32];
    __shared__ __align__(16) unsigned short Ls[2][256 * 32];
    const int tid = threadIdx.x, lane = tid & 63, w = tid >> 6;
    const int l15 = lane & 15, lg = lane >> 4;
    const int wr = w >> 1, wc = w & 1;          // 4x64-row x 2x128-col wave grid
    const int srow = tid >> 1, shalf = tid & 1; // staging: row, 16-col half
    const int m4 = (srow >> 1) & 3;             // swizzle key for this row
    const float* xb = x + (size_t)b * 256 * HW + (size_t)srow * HW + kc * 512 + shalf * 16;
    f32x4 acc[4][8] = {};
    float rs = 0.f;
    float4 ld[4];

#define LOADR(kstep)                                                            \
    {                                                                           \
        const float4* src = reinterpret_cast<const float4*>(xb + (kstep) * 32); \
        ld[0] = src[0]; ld[1] = src[1]; ld[2] = src[2]; ld[3] = src[3];         \
    }
#define STORE(sel)                                                              \
    {                                                                           \
        _Pragma("unroll")                                                       \
        for (int cq = 0; cq < 2; ++cq) {                                        \
            const float vv[8] = {ld[2*cq].x, ld[2*cq].y, ld[2*cq].z, ld[2*cq].w,\
                                 ld[2*cq+1].x, ld[2*cq+1].y, ld[2*cq+1].z, ld[2*cq+1].w}; \
            uint4 Hv, Lv;                                                       \
            uint32_t* Hp = reinterpret_cast<uint32_t*>(&Hv);                    \
            uint32_t* Lp = reinterpret_cast<uint32_t*>(&Lv);                    \
            _Pragma("unroll")                                                   \
            for (int p = 0; p < 4; ++p) {                                       \
                const float a0 = vv[2*p], a1 = vv[2*p+1];                       \
                const uint32_t hp = pk_bf16(a0, a1);                            \
                const float lo0 = a0 - ubf2f(hp << 16);                         \
                const float lo1 = a1 - ubf2f(hp & 0xffff0000u);                 \
                Hp[p] = hp;                                                     \
                Lp[p] = pk_bf16(lo0, lo1);                                      \
                rs += a0 + a1;                                                  \
            }                                                                   \
            const int slot = ((shalf * 2 + cq) ^ m4) << 4;                      \
            *reinterpret_cast<uint4*>((char*)(&Hs[sel][0]) + srow * 64 + slot) = Hv; \
            *reinterpret_cast<uint4*>((char*)(&Ls[sel][0]) + srow * 64 + slot) = Lv; \
        }                                                                       \
    }
#define DO_MFMA(sel)                                                            \
    {                                                                           \
        bf16x8 fah[4], fal[4];                                                  \
        _Pragma("unroll")                                                       \
        for (int i = 0; i < 4; ++i) {                                           \
            const int row = wr * 64 + i * 16 + l15;                             \
            const int off = row * 64 + ((lg ^ ((row >> 1) & 3)) << 4);          \
            fah[i] = *reinterpret_cast<const bf16x8*>((const char*)&Hs[sel][0] + off); \
            fal[i] = *reinterpret_cast<const bf16x8*>((const char*)&Ls[sel][0] + off); \
        }                                                                       \
        _Pragma("unroll")                                                       \
        for (int j = 0; j < 8; ++j) {                                           \
            const int row = wc * 128 + j * 16 + l15;                            \
            const int off = row * 64 + ((lg ^ ((row >> 1) & 3)) << 4);          \
            const bf16x8 fbh = *reinterpret_cast<const bf16x8*>((const char*)&Hs[sel][0] + off); \
            const bf16x8 fbl = *reinterpret_cast<const bf16x8*>((const char*)&Ls[sel][0] + off); \
            _Pragma("unroll")                                                   \
            for (int i = 0; i < 4; ++i) {                                       \
                acc[i][j] = __builtin_amdgcn_mfma_f32_16x16x32_bf16(fah[i], fbh, acc[i][j], 0, 0, 0); \
                acc[i][j] = __builtin_amdgcn_mfma_f32_16x16x32_bf16(fah[i], fbl, acc[i][j], 0, 0, 0); \
                acc[i][j] = __builtin_amdgcn_mfma_f32_16x16x32_bf16(fal[i], fbh, acc[i][j], 0, 0, 0); \
            }                                                                   \
        }                                                                       \
    }

    LOADR(0);
    STORE(0);
    __syncthreads();
    for (int t = 0; t < 16; ++t) {
        if (t < 15) LOADR(t + 1);
        DO_MFMA(t & 1);
        if (t < 15) STORE((t + 1) & 1);
        __syncthreads();
    }
#undef LOADR
#undef STORE
#undef DO_MFMA

    // row-sum partials: threads 2r,2r+1 share row r
    rs += __shfl_xor(rs, 1);
    if ((tid & 1) == 0) parts_s[(size_t)(b * 32 + kc) * 256 + srow] = rs;

    float* pw = partG + (size_t)(b * 32 + kc) * 65536;
    #pragma unroll
    for (int i = 0; i < 4; ++i)
        #pragma unroll
        for (int rr = 0; rr < 4; ++rr) {
            const int m = wr * 64 + i * 16 + lg * 4 + rr;
            #pragma unroll
            for (int j = 0; j < 8; ++j)
                pw[m * 256 + wc * 128 + j * 16 + l15] = acc[i][j][rr];
        }
}

// ---------------- K2: G = sum over 32 chunks of partG (float4 vectorized)
__global__ __launch_bounds__(256) void greduce(
        const float4* __restrict__ partG4, float4* __restrict__ G4) {
    const int g = blockIdx.x * 256 + threadIdx.x;   // 131072 float4s
    const int b = g >> 14, i4 = g & 16383;
    float4 a = make_float4(0.f, 0.f, 0.f, 0.f);
    #pragma unroll 8
    for (int kc = 0; kc < 32; ++kc) {
        const float4 v = partG4[(size_t)(b * 32 + kc) * 16384 + i4];
        a.x += v.x; a.y += v.y; a.z += v.z; a.w += v.w;
    }
    G4[g] = a;
}

// ---------------- K3: fused tgemm + logits + softmax (+ s-reduce) per (b,h)
__global__ __launch_bounds__(512) void tlogits(
        const float* __restrict__ G, const float* __restrict__ Wqkv,
        const float* __restrict__ bqkv, const float* __restrict__ parts_s,
        float* __restrict__ attn) {
    const int bh = blockIdx.x, b = bh >> 2, h = bh & 3;
    const int tid = threadIdx.x;
    __shared__ __align__(16) float SM[38528];     // 154 KB
    float* R1 = SM;            // [64][264]: G chunk, then T
    float* R2 = SM + 16896;    // [256][66]: Wk^T
    float* WQ = SM + 33792;    // [64][68]: Wq chunk; later lgs [64][65]
    float* SB = SM + 38144;    // 256
    float* QS = SM + 38400;    // 64
    float* KS = SM + 38464;    // 64
    const float* Gb = G + (size_t)b * 65536;
    const float* Wq = Wqkv + (size_t)(h * 64) * 256;
    const float* Wk = Wqkv + (size_t)(256 + h * 64) * 256;

    if (tid < 256) {   // SB = s_b (reduce parts)
        float a = 0.f;
        #pragma unroll
        for (int kc = 0; kc < 32; ++kc)
            a += parts_s[(size_t)(b * 32 + kc) * 256 + tid];
        SB[tid] = a;
    }
    {   // stage Wk^T -> R2
        const int e = tid >> 3, cq = (tid & 7) * 32;
        #pragma unroll
        for (int q = 0; q < 8; ++q) {
            const float4 w4 = *reinterpret_cast<const float4*>(Wk + (size_t)e * 256 + cq + q * 4);
            R2[(cq + q * 4 + 0) * 66 + e] = w4.x;
            R2[(cq + q * 4 + 1) * 66 + e] = w4.y;
            R2[(cq + q * 4 + 2) * 66 + e] = w4.z;
            R2[(cq + q * 4 + 3) * 66 + e] = w4.w;
        }
    }
    __syncthreads();
    if (tid < 64) {   // ks = Wk s_b
        float a = 0.f;
        for (int c = 0; c < 256; ++c) a += R2[c * 66 + tid] * SB[c];
        KS[tid] = a;
    }

    // phase A: T[d][c'] = sum_c Wq[d][c] G[c][c']; thread owns d=dq*4+i, c'=cb+32*jj
    const int dq = tid >> 5, cb = tid & 31;
    float tacc[4][8] = {};
    float qacc = 0.f;
    for (int cc = 0; cc < 4; ++cc) {
        {   // stage G rows [cc*64,+64) -> R1
            const int r = tid >> 3, cq = (tid & 7) * 32;
            #pragma unroll
            for (int q = 0; q < 8; ++q)
                *reinterpret_cast<float4*>(&R1[r * 264 + cq + q * 4]) =
                    *reinterpret_cast<const float4*>(Gb + (size_t)(cc * 64 + r) * 256 + cq + q * 4);
        }
        {   // stage Wq chunk cols -> WQ
            const int r = tid >> 3, c8 = (tid & 7) * 8;
            *reinterpret_cast<float4*>(&WQ[r * 68 + c8]) =
                *reinterpret_cast<const float4*>(Wq + (size_t)r * 256 + cc * 64 + c8);
            *reinterpret_cast<float4*>(&WQ[r * 68 + c8 + 4]) =
                *reinterpret_cast<const float4*>(Wq + (size_t)r * 256 + cc * 64 + c8 + 4);
        }
        __syncthreads();
        for (int c = 0; c < 64; ++c) {
            float wv[4];
            #pragma unroll
            for (int i = 0; i < 4; ++i) wv[i] = WQ[(dq * 4 + i) * 68 + c];
            #pragma unroll
            for (int jj = 0; jj < 8; ++jj) {
                const float gv = R1[c * 264 + cb + 32 * jj];
                #pragma unroll
                for (int i = 0; i < 4; ++i) tacc[i][jj] += wv[i] * gv;
            }
        }
        if (tid < 64) {   // qs partial on this Wq chunk
            float a = 0.f;
            for (int c = 0; c < 64; ++c) a += WQ[tid * 68 + c] * SB[cc * 64 + c];
            qacc += a;
        }
        __syncthreads();
    }
    if (tid < 64) QS[tid] = qacc;
    #pragma unroll
    for (int i = 0; i < 4; ++i)
        #pragma unroll
        for (int jj = 0; jj < 8; ++jj)
            R1[(dq * 4 + i) * 264 + cb + 32 * jj] = tacc[i][jj];   // T -> R1
    __syncthreads();

    // phase B: logits[d][e] = sum_c' T[d][c'] Wk[e][c']
    const int e2 = tid & 31;
    float lacc[4][2] = {};
    for (int c = 0; c < 256; ++c) {
        float tv[4];
        #pragma unroll
        for (int i = 0; i < 4; ++i) tv[i] = R1[(dq * 4 + i) * 264 + c];
        #pragma unroll
        for (int k = 0; k < 2; ++k) {
            const float wv = R2[c * 66 + e2 * 2 + k];
            #pragma unroll
            for (int i = 0; i < 4; ++i) lacc[i][k] += tv[i] * wv;
        }
    }
    float* lgs = WQ;   // reuse as [64][65]
    const float* bq = bqkv + h * 64;
    const float* bk = bqkv + 256 + h * 64;
    #pragma unroll
    for (int i = 0; i < 4; ++i) {
        const int d = dq * 4 + i;
        #pragma unroll
        for (int k = 0; k < 2; ++k) {
            const int e = e2 * 2 + k;
            lgs[d * 65 + e] = SCALE_F * (lacc[i][k] + bq[d] * KS[e] + bk[e] * QS[d] + NF * bq[d] * bk[e]);
        }
    }
    __syncthreads();
    if (tid < 64) {
        float m = -1e30f;
        for (int e = 0; e < 64; ++e) m = fmaxf(m, lgs[tid * 65 + e]);
        float sum = 0.f;
        for (int e = 0; e < 64; ++e) {
            const float ex = __expf(lgs[tid * 65 + e] - m);
            sum += ex;
            lgs[tid * 65 + e] = ex;
        }
        const float inv = 1.f / sum;
        float* ar = attn + ((size_t)bh * 64 + tid) * 64;
        for (int e = 0; e < 64; ++e) ar[e] = lgs[tid * 65 + e] * inv;
    }
}

// ---------------- K4: fused build_M + build_P + cvec; block = (b, 16-o slice)
__global__ __launch_bounds__(256) void buildMP(
        const float* __restrict__ attn, const float* __restrict__ Wproj,
        const float* __restrict__ Wqkv, const float* __restrict__ bqkv,
        const float* __restrict__ bproj, unsigned short* __restrict__ P,
        float* __restrict__ cvec) {
    const int blk = blockIdx.x;          // 128 = 8 b x 16 slices
    const int b = blk >> 4, o0 = (blk & 15) * 16;
    const int tid = threadIdx.x;
    __shared__ __align__(16) float U[16512];    // attn[b] (16384) then Wv chunk [64][258]
    __shared__ __align__(16) float WpL[16 * 258];
    __shared__ __align__(16) float ML[16 * 258];
    const int og = tid >> 6, cb = tid & 63;     // o = o0+og*4+i, he/c = j*64+cb

    {   // stage attn[b]
        const float* ab = attn + (size_t)b * 16384;
        #pragma unroll
        for (int q = 0; q < 16; ++q)
            *reinterpret_cast<float4*>(&U[tid * 64 + q * 4]) =
                *reinterpret_cast<const float4*>(ab + tid * 64 + q * 4);
    }
    {   // stage Wproj slice [16][256]
        const int r = tid >> 4, cc = (tid & 15) * 16;
        #pragma unroll
        for (int q = 0; q < 4; ++q)
            *reinterpret_cast<float4*>(&WpL[r * 258 + cc + q * 4]) =
                *reinterpret_cast<const float4*>(Wproj + (size_t)(o0 + r) * 256 + cc + q * 4);
    }
    __syncthreads();

    // phase 1: M[o][j*64+cb] = sum_d Wp[o][j*64+d] * att[j][d][cb]
    float macc[4][4] = {};
    #pragma unroll
    for (int j = 0; j < 4; ++j)
        for (int d = 0; d < 64; ++d) {
            const float a = U[j * 4096 + d * 64 + cb];
            #pragma unroll
            for (int i = 0; i < 4; ++i)
                macc[i][j] += WpL[(og * 4 + i) * 258 + j * 64 + d] * a;
        }
    #pragma unroll
    for (int i = 0; i < 4; ++i)
        #pragma unroll
        for (int j = 0; j < 4; ++j)
            ML[(og * 4 + i) * 258 + j * 64 + cb] = macc[i][j];
    __syncthreads();

    if (tid < 16) {   // cvec
        const int o = o0 + tid;
        float a = bproj[o];
        for (int he = 0; he < 256; ++he) a += ML[tid * 258 + he] * bqkv[512 + he];
        cvec[b * 256 + o] = a;
    }

    // phase 2: P[o][j*64+cb] = sum_he M[o][he] * Wv[he][j*64+cb]
    float pacc[4][4] = {};
    for (int ch = 0; ch < 4; ++ch) {
        {   // stage Wv chunk rows [ch*64,+64) into U [64][258]
            const int r = tid >> 2, cc = (tid & 3) * 64;
            #pragma unroll
            for (int q = 0; q < 16; ++q)
                *reinterpret_cast<float4*>(&U[r * 258 + cc + q * 4]) =
                    *reinterpret_cast<const float4*>(Wqkv + (size_t)(512 + ch * 64 + r) * 256 + cc + q * 4);
        }
        __syncthreads();
        for (int he = 0; he < 64; ++he) {
            float mw[4];
            #pragma unroll
            for (int i = 0; i < 4; ++i) mw[i] = ML[(og * 4 + i) * 258 + ch * 64 + he];
            #pragma unroll
            for (int j = 0; j < 4; ++j) {
                const float wv = U[he * 258 + j * 64 + cb];
                #pragma unroll
                for (int i = 0; i < 4; ++i) pacc[i][j] += mw[i] * wv;
            }
        }
        __syncthreads();
    }
    unsigned short* Pb = P + (size_t)b * 65536;
    #pragma unroll
    for (int i = 0; i < 4; ++i)
        #pragma unroll
        for (int j = 0; j < 4; ++j)
            Pb[(size_t)(o0 + og * 4 + i) * 256 + j * 64 + cb] = f2bf(pacc[i][j]);
}

// ---------------- K5 v7: out = P x + cvec. 64-n tile -> 32 KB LDS -> 4 blocks/CU.
// Rolling 1-deep stage with cvt_pk, per-step P loads (VGPR <= 64), single barrier,
// operand-swapped MFMA, float4 stores.
__global__ __launch_bounds__(512) void out_gemm(
        const unsigned short* __restrict__ P, const float* __restrict__ x,
        const float* __restrict__ cvec, float* __restrict__ out) {
    const int n0 = blockIdx.x * 64;
    const int b  = blockIdx.y;
    __shared__ __align__(16) unsigned short Bs[8 * 64 * 32];  // 32 KB: [s][n][32k] swizzled
    const int tid = threadIdx.x, lane = tid & 63, w = tid >> 6;
    const int wr = w >> 1, wc = w & 1;          // 4x64(m) x 2x32(n) wave grid
    const int l15 = lane & 15, lg = lane >> 4;
    const unsigned short* Pb = P + (size_t)b * 65536;

    // ---- stage 64n x 256k, rolling 1-deep prefetch, cvt_pk, no intra-stage barrier
    {
        const int sn = tid & 63;                   // n
        const int sg = tid >> 6;                   // 0..7, 4 k each within 32-k step
        const int wbyte = (((sg >> 1) ^ ((sn >> 1) & 3)) << 4) + (sg & 1) * 8;
        const float* xcol = x + (size_t)b * 256 * HW + n0 + sn;
        float bv[2][4];
        #pragma unroll
        for (int i = 0; i < 4; ++i)
            bv[0][i] = xcol[(size_t)(sg * 4 + i) * HW];
        #pragma unroll
        for (int s = 0; s < 8; ++s) {
            if (s < 7) {
                #pragma unroll
                for (int i = 0; i < 4; ++i)
                    bv[(s + 1) & 1][i] = xcol[(size_t)((s + 1) * 32 + sg * 4 + i) * HW];
            }
            uint2 Bu;
            Bu.x = pk_bf16(bv[s & 1][0], bv[s & 1][1]);
            Bu.y = pk_bf16(bv[s & 1][2], bv[s & 1][3]);
            *reinterpret_cast<uint2*>((char*)Bs + s * 4096 + sn * 64 + wbyte) = Bu;
        }
    }
    __syncthreads();

    // ---- compute: K=256 straight through, 64 MFMA/wave
    f32x4 acc[4][2] = {};   // [m-frag][n-frag]; lane: m = +l15, n = +lg*4+reg
    #pragma unroll
    for (int s = 0; s < 8; ++s) {
        bf16x8 fp[4];   // P rows (B operand: cols = m)
        #pragma unroll
        for (int i = 0; i < 4; ++i)
            fp[i] = *reinterpret_cast<const bf16x8*>(
                Pb + (size_t)(wr * 64 + i * 16 + l15) * 256 + s * 32 + lg * 8);
        #pragma unroll
        for (int j = 0; j < 2; ++j) {
            const int row = wc * 32 + j * 16 + l15;
            const bf16x8 fx = *reinterpret_cast<const bf16x8*>(
                (const char*)Bs + s * 4096 + row * 64 + ((lg ^ ((row >> 1) & 3)) << 4));
            #pragma unroll
            for (int i = 0; i < 4; ++i)
                acc[i][j] = __builtin_amdgcn_mfma_f32_16x16x32_bf16(fx, fp[i], acc[i][j], 0, 0, 0);
        }
    }

    float* ob = out + (size_t)b * 256 * HW;
    #pragma unroll
    for (int i = 0; i < 4; ++i) {
        const int m = wr * 64 + i * 16 + l15;
        const float bp = cvec[b * 256 + m];
        #pragma unroll
        for (int j = 0; j < 2; ++j) {
            const int n = n0 + wc * 32 + j * 16 + lg * 4;
            float4 o4;
            o4.x = acc[i][j][0] + bp;
            o4.y = acc[i][j][1] + bp;
            o4.z = acc[i][j][2] + bp;
            o4.w = acc[i][j][3] + bp;
            *reinterpret_cast<float4*>(ob + (size_t)m * HW + n) = o4;
        }
    }
}

extern "C" void kernel_launch(void* const* d_in, const int* in_sizes, int n_in,
                              void* d_out, int out_size, void* d_ws, size_t ws_size,
                              hipStream_t stream) {
    const float* x     = (const float*)d_in[0];
    const float* Wqkv  = (const float*)d_in[1];
    const float* bqkv  = (const float*)d_in[2];
    const float* Wproj = (const float*)d_in[3];
    const float* bproj = (const float*)d_in[4];
    float* out = (float*)d_out;

    // ws layout (bytes):
    //   partG  :        0   67108864   (8*32*256*256 f32)
    //   G      : 67108864    2097152
    //   attn   : 69206016     524288
    //   P      : 69730304    1048576
    //   cvec   : 70778880       8192
    //   partsS : 70787072     262144   -> ~67.7 MiB
    char* ws = (char*)d_ws;
    float* partG   = (float*)(ws);
    float* G       = (float*)(ws + 67108864);
    float* attn    = (float*)(ws + 69206016);
    unsigned short* P = (unsigned short*)(ws + 69730304);
    float* cvec    = (float*)(ws + 70778880);
    float* parts_s = (float*)(ws + 70787072);

    gram    <<<dim3(32, 8),  512, 0, stream>>>(x, partG, parts_s);
    greduce <<<512,          256, 0, stream>>>((const float4*)partG, (float4*)G);
    tlogits <<<32,           512, 0, stream>>>(G, Wqkv, bqkv, parts_s, attn);
    buildMP <<<128,          256, 0, stream>>>(attn, Wproj, Wqkv, bqkv, bproj, P, cvec);
    out_gemm<<<dim3(256, 8), 512, 0, stream>>>(P, x, cvec, out);
}

// Round 14
// 199.638 us; speedup vs baseline: 1.2153x; 1.1622x over previous
//
#include <hip/hip_runtime.h>
#include <hip/hip_bf16.h>
#include <stdint.h>

// B=8, C=256, HW=16384, HEADS=4, HEAD_DIM=64, SCALE=1/8.
// G[b]=x x^T (split-bf16 MFMA, in-register hi/lo split of fp32 x);
// T = Wq G; logits = T Wk^T (+bias); attn = softmax;
// M = Wproj blockdiag(attn); P = M Wv; out = P x + (M bv + bproj).

#define HW 16384
#define SCALE_F 0.125f
#define NF 16384.0f

typedef __attribute__((ext_vector_type(8))) short bf16x8;
typedef __attribute__((ext_vector_type(4))) float f32x4;

__device__ __forceinline__ unsigned short f2bf(float f) {
    union { float f; uint32_t u; } v; v.f = f;
    uint32_t u = v.u;
    return (unsigned short)((u + 0x7fffu + ((u >> 16) & 1u)) >> 16);  // RNE
}
__device__ __forceinline__ float bf2f(unsigned short s) {
    union { uint32_t u; float f; } v; v.u = ((uint32_t)s) << 16;
    return v.f;
}
// packed f32x2 -> bf16x2 (RNE, hardware v_cvt_pk_bf16_f32); low16 = a, high16 = b
__device__ __forceinline__ uint32_t pk_bf16(float a, float b) {
    __hip_bfloat162 h = __float22bfloat162_rn(make_float2(a, b));
    union { __hip_bfloat162 h; uint32_t u; } c; c.h = h; return c.u;
}
__device__ __forceinline__ float ubf2f(uint32_t hibits) {   // bf16 bits already in [31:16]
    union { uint32_t u; float f; } v; v.u = hibits; return v.f;
}

// ---------------- K1: Gram (R11 best: 32 K-chunks of 512, 256 blocks); cvt_pk staging
__global__ __launch_bounds__(512) void gram(
        const float* __restrict__ x, float* __restrict__ partG,
        float* __restrict__ parts_s) {
    const int kc = blockIdx.x;    // 0..31, K-chunk of 512
    const int b  = blockIdx.y;
    __shared__ __align__(16) unsigned short Hs[2][256 * 32];
    __shared__ __align__(16) unsigned short Ls[2][256 * 32];
    const int tid = threadIdx.x, lane = tid & 63, w = tid >> 6;
    const int l15 = lane & 15, lg = lane >> 4;
    const int wr = w >> 1, wc = w & 1;          // 4x64-row x 2x128-col wave grid
    const int srow = tid >> 1, shalf = tid & 1; // staging: row, 16-col half
    const int m4 = (srow >> 1) & 3;             // swizzle key for this row
    const float* xb = x + (size_t)b * 256 * HW + (size_t)srow * HW + kc * 512 + shalf * 16;
    f32x4 acc[4][8] = {};
    float rs = 0.f;
    float4 ld[4];

#define LOADR(kstep)                                                            \
    {                                                                           \
        const float4* src = reinterpret_cast<const float4*>(xb + (kstep) * 32); \
        ld[0] = src[0]; ld[1] = src[1]; ld[2] = src[2]; ld[3] = src[3];         \
    }
#define STORE(sel)                                                              \
    {                                                                           \
        _Pragma("unroll")                                                       \
        for (int cq = 0; cq < 2; ++cq) {                                        \
            const float vv[8] = {ld[2*cq].x, ld[2*cq].y, ld[2*cq].z, ld[2*cq].w,\
                                 ld[2*cq+1].x, ld[2*cq+1].y, ld[2*cq+1].z, ld[2*cq+1].w}; \
            uint4 Hv, Lv;                                                       \
            uint32_t* Hp = reinterpret_cast<uint32_t*>(&Hv);                    \
            uint32_t* Lp = reinterpret_cast<uint32_t*>(&Lv);                    \
            _Pragma("unroll")                                                   \
            for (int p = 0; p < 4; ++p) {                                       \
                const float a0 = vv[2*p], a1 = vv[2*p+1];                       \
                const uint32_t hp = pk_bf16(a0, a1);                            \
                const float lo0 = a0 - ubf2f(hp << 16);                         \
                const float lo1 = a1 - ubf2f(hp & 0xffff0000u);                 \
                Hp[p] = hp;                                                     \
                Lp[p] = pk_bf16(lo0, lo1);                                      \
                rs += a0 + a1;                                                  \
            }                                                                   \
            const int slot = ((shalf * 2 + cq) ^ m4) << 4;                      \
            *reinterpret_cast<uint4*>((char*)(&Hs[sel][0]) + srow * 64 + slot) = Hv; \
            *reinterpret_cast<uint4*>((char*)(&Ls[sel][0]) + srow * 64 + slot) = Lv; \
        }                                                                       \
    }
#define DO_MFMA(sel)                                                            \
    {                                                                           \
        bf16x8 fah[4], fal[4];                                                  \
        _Pragma("unroll")                                                       \
        for (int i = 0; i < 4; ++i) {                                           \
            const int row = wr * 64 + i * 16 + l15;                             \
            const int off = row * 64 + ((lg ^ ((row >> 1) & 3)) << 4);          \
            fah[i] = *reinterpret_cast<const bf16x8*>((const char*)&Hs[sel][0] + off); \
            fal[i] = *reinterpret_cast<const bf16x8*>((const char*)&Ls[sel][0] + off); \
        }                                                                       \
        _Pragma("unroll")                                                       \
        for (int j = 0; j < 8; ++j) {                                           \
            const int row = wc * 128 + j * 16 + l15;                            \
            const int off = row * 64 + ((lg ^ ((row >> 1) & 3)) << 4);          \
            const bf16x8 fbh = *reinterpret_cast<const bf16x8*>((const char*)&Hs[sel][0] + off); \
            const bf16x8 fbl = *reinterpret_cast<const bf16x8*>((const char*)&Ls[sel][0] + off); \
            _Pragma("unroll")                                                   \
            for (int i = 0; i < 4; ++i) {                                       \
                acc[i][j] = __builtin_amdgcn_mfma_f32_16x16x32_bf16(fah[i], fbh, acc[i][j], 0, 0, 0); \
                acc[i][j] = __builtin_amdgcn_mfma_f32_16x16x32_bf16(fah[i], fbl, acc[i][j], 0, 0, 0); \
                acc[i][j] = __builtin_amdgcn_mfma_f32_16x16x32_bf16(fal[i], fbh, acc[i][j], 0, 0, 0); \
            }                                                                   \
        }                                                                       \
    }

    LOADR(0);
    STORE(0);
    __syncthreads();
    for (int t = 0; t < 16; ++t) {
        if (t < 15) LOADR(t + 1);
        DO_MFMA(t & 1);
        if (t < 15) STORE((t + 1) & 1);
        __syncthreads();
    }
#undef LOADR
#undef STORE
#undef DO_MFMA

    // row-sum partials: threads 2r,2r+1 share row r
    rs += __shfl_xor(rs, 1);
    if ((tid & 1) == 0) parts_s[(size_t)(b * 32 + kc) * 256 + srow] = rs;

    float* pw = partG + (size_t)(b * 32 + kc) * 65536;
    #pragma unroll
    for (int i = 0; i < 4; ++i)
        #pragma unroll
        for (int rr = 0; rr < 4; ++rr) {
            const int m = wr * 64 + i * 16 + lg * 4 + rr;
            #pragma unroll
            for (int j = 0; j < 8; ++j)
                pw[m * 256 + wc * 128 + j * 16 + l15] = acc[i][j][rr];
        }
}

// ---------------- K2: G = sum over 32 chunks of partG (float4 vectorized)
__global__ __launch_bounds__(256) void greduce(
        const float4* __restrict__ partG4, float4* __restrict__ G4) {
    const int g = blockIdx.x * 256 + threadIdx.x;   // 131072 float4s
    const int b = g >> 14, i4 = g & 16383;
    float4 a = make_float4(0.f, 0.f, 0.f, 0.f);
    #pragma unroll 8
    for (int kc = 0; kc < 32; ++kc) {
        const float4 v = partG4[(size_t)(b * 32 + kc) * 16384 + i4];
        a.x += v.x; a.y += v.y; a.z += v.z; a.w += v.w;
    }
    G4[g] = a;
}

// ---------------- K3 v2: fused T-slice + logits + softmax per (b,h,d-quarter); 128 blocks
__global__ __launch_bounds__(256) void tlogits(
        const float* __restrict__ G, const float* __restrict__ Wqkv,
        const float* __restrict__ bqkv, const float* __restrict__ parts_s,
        float* __restrict__ attn) {
    const int blk = blockIdx.x;            // 128 = bh*4 + d-quarter
    const int bh = blk >> 2, d0 = (blk & 3) * 16;
    const int b = bh >> 2, h = bh & 3;
    const int tid = threadIdx.x;
    __shared__ __align__(16) float WkT[256 * 68];   // Wk^T [c][e], pad 68 (16B-aligned rows)
    __shared__ __align__(16) float Gs[32 * 264];    // G chunk rows; later Ts[16][264]
    __shared__ __align__(16) float Wqs[16 * 264];   // Wq slice [16][256]
    __shared__ float lgs[16 * 65];
    __shared__ float SB[256];
    __shared__ float QS[16], KS[64];
    const float* Gb = G + (size_t)b * 65536;
    const float* Wq = Wqkv + (size_t)(h * 64 + d0) * 256;   // 16 rows
    const float* Wk = Wqkv + (size_t)(256 + h * 64) * 256;

    {   // SB = s_b (reduce parts)
        float a = 0.f;
        #pragma unroll 8
        for (int kc = 0; kc < 32; ++kc)
            a += parts_s[(size_t)(b * 32 + kc) * 256 + tid];
        SB[tid] = a;
    }
    {   // stage Wk^T -> WkT
        const int e = tid >> 2, cq = (tid & 3) * 64;
        for (int q = 0; q < 64; q += 4) {
            const float4 w4 = *reinterpret_cast<const float4*>(Wk + (size_t)e * 256 + cq + q);
            WkT[(cq + q + 0) * 68 + e] = w4.x;
            WkT[(cq + q + 1) * 68 + e] = w4.y;
            WkT[(cq + q + 2) * 68 + e] = w4.z;
            WkT[(cq + q + 3) * 68 + e] = w4.w;
        }
    }
    {   // stage Wq slice [16][256]
        const int r = tid >> 4, cq = (tid & 15) * 16;
        #pragma unroll
        for (int q = 0; q < 16; q += 4)
            *reinterpret_cast<float4*>(&Wqs[r * 264 + cq + q]) =
                *reinterpret_cast<const float4*>(Wq + (size_t)r * 256 + cq + q);
    }
    __syncthreads();
    if (tid < 64) {        // KS = Wk s_b
        float a = 0.f;
        for (int c = 0; c < 256; ++c) a += WkT[c * 68 + tid] * SB[c];
        KS[tid] = a;
    } else if (tid >= 240) {   // QS (d-slice) = Wq s_b
        const int d = tid - 240;
        float a = 0.f;
        for (int c = 0; c < 256; ++c) a += Wqs[d * 264 + c] * SB[c];
        QS[d] = a;
    }

    // phase A: T[d][cp] = sum_c Wq[d][c] G[c][cp]; thread = (d = tid>>4, cp = (tid&15)+16j)
    const int d = tid >> 4, cp0 = tid & 15;
    float tacc[16] = {};
    for (int cc = 0; cc < 8; ++cc) {
        {   // stage G rows [cc*32, +32)
            const int r = tid >> 3, cq = (tid & 7) * 32;
            #pragma unroll
            for (int q = 0; q < 32; q += 4)
                *reinterpret_cast<float4*>(&Gs[r * 264 + cq + q]) =
                    *reinterpret_cast<const float4*>(Gb + (size_t)(cc * 32 + r) * 256 + cq + q);
        }
        __syncthreads();
        for (int c = 0; c < 32; ++c) {
            const float wv = Wqs[d * 264 + cc * 32 + c];
            #pragma unroll
            for (int j = 0; j < 16; ++j)
                tacc[j] += wv * Gs[c * 264 + cp0 + 16 * j];
        }
        __syncthreads();
    }
    // write T slice into Gs (reuse as Ts[16][264])
    #pragma unroll
    for (int j = 0; j < 16; ++j)
        Gs[d * 264 + cp0 + 16 * j] = tacc[j];
    __syncthreads();

    // phase B: logits[d][e] = sum_c Ts[d][c] WkT[c][e]; thread = (d, e0 = (tid&15)*4)
    float lacc[4] = {};
    const int e0 = (tid & 15) * 4;
    for (int c = 0; c < 256; ++c) {
        const float tv = Gs[d * 264 + c];
        const float4 wv = *reinterpret_cast<const float4*>(&WkT[c * 68 + e0]);
        lacc[0] += tv * wv.x; lacc[1] += tv * wv.y;
        lacc[2] += tv * wv.z; lacc[3] += tv * wv.w;
    }
    const float* bq = bqkv + h * 64 + d0;
    const float* bk = bqkv + 256 + h * 64;
    #pragma unroll
    for (int k = 0; k < 4; ++k) {
        const int e = e0 + k;
        lgs[d * 65 + e] = SCALE_F * (lacc[k] + bq[d] * KS[e] + bk[e] * QS[d] + NF * bq[d] * bk[e]);
    }
    __syncthreads();
    if (tid < 16) {
        float m = -1e30f;
        for (int e = 0; e < 64; ++e) m = fmaxf(m, lgs[tid * 65 + e]);
        float sum = 0.f;
        for (int e = 0; e < 64; ++e) {
            const float ex = __expf(lgs[tid * 65 + e] - m);
            sum += ex;
            lgs[tid * 65 + e] = ex;
        }
        const float inv = 1.f / sum;
        float* ar = attn + ((size_t)bh * 64 + d0 + tid) * 64;
        for (int e = 0; e < 64; ++e) ar[e] = lgs[tid * 65 + e] * inv;
    }
}

// ---------------- K4: fused build_M + build_P + cvec; block = (b, 16-o slice)
__global__ __launch_bounds__(256) void buildMP(
        const float* __restrict__ attn, const float* __restrict__ Wproj,
        const float* __restrict__ Wqkv, const float* __restrict__ bqkv,
        const float* __restrict__ bproj, unsigned short* __restrict__ P,
        float* __restrict__ cvec) {
    const int blk = blockIdx.x;          // 128 = 8 b x 16 slices
    const int b = blk >> 4, o0 = (blk & 15) * 16;
    const int tid = threadIdx.x;
    __shared__ __align__(16) float U[16512];    // attn[b] (16384) then Wv chunk [64][258]
    __shared__ __align__(16) float WpL[16 * 258];
    __shared__ __align__(16) float ML[16 * 258];
    const int og = tid >> 6, cb = tid & 63;     // o = o0+og*4+i, he/c = j*64+cb

    {   // stage attn[b]
        const float* ab = attn + (size_t)b * 16384;
        #pragma unroll
        for (int q = 0; q < 16; ++q)
            *reinterpret_cast<float4*>(&U[tid * 64 + q * 4]) =
                *reinterpret_cast<const float4*>(ab + tid * 64 + q * 4);
    }
    {   // stage Wproj slice [16][256]
        const int r = tid >> 4, cc = (tid & 15) * 16;
        #pragma unroll
        for (int q = 0; q < 4; ++q)
            *reinterpret_cast<float4*>(&WpL[r * 258 + cc + q * 4]) =
                *reinterpret_cast<const float4*>(Wproj + (size_t)(o0 + r) * 256 + cc + q * 4);
    }
    __syncthreads();

    // phase 1: M[o][j*64+cb] = sum_d Wp[o][j*64+d] * att[j][d][cb]
    float macc[4][4] = {};
    #pragma unroll
    for (int j = 0; j < 4; ++j)
        for (int d = 0; d < 64; ++d) {
            const float a = U[j * 4096 + d * 64 + cb];
            #pragma unroll
            for (int i = 0; i < 4; ++i)
                macc[i][j] += WpL[(og * 4 + i) * 258 + j * 64 + d] * a;
        }
    #pragma unroll
    for (int i = 0; i < 4; ++i)
        #pragma unroll
        for (int j = 0; j < 4; ++j)
            ML[(og * 4 + i) * 258 + j * 64 + cb] = macc[i][j];
    __syncthreads();

    if (tid < 16) {   // cvec
        const int o = o0 + tid;
        float a = bproj[o];
        for (int he = 0; he < 256; ++he) a += ML[tid * 258 + he] * bqkv[512 + he];
        cvec[b * 256 + o] = a;
    }

    // phase 2: P[o][j*64+cb] = sum_he M[o][he] * Wv[he][j*64+cb]
    float pacc[4][4] = {};
    for (int ch = 0; ch < 4; ++ch) {
        {   // stage Wv chunk rows [ch*64,+64) into U [64][258]
            const int r = tid >> 2, cc = (tid & 3) * 64;
            #pragma unroll
            for (int q = 0; q < 16; ++q)
                *reinterpret_cast<float4*>(&U[r * 258 + cc + q * 4]) =
                    *reinterpret_cast<const float4*>(Wqkv + (size_t)(512 + ch * 64 + r) * 256 + cc + q * 4);
        }
        __syncthreads();
        for (int he = 0; he < 64; ++he) {
            float mw[4];
            #pragma unroll
            for (int i = 0; i < 4; ++i) mw[i] = ML[(og * 4 + i) * 258 + ch * 64 + he];
            #pragma unroll
            for (int j = 0; j < 4; ++j) {
                const float wv = U[he * 258 + j * 64 + cb];
                #pragma unroll
                for (int i = 0; i < 4; ++i) pacc[i][j] += mw[i] * wv;
            }
        }
        __syncthreads();
    }
    unsigned short* Pb = P + (size_t)b * 65536;
    #pragma unroll
    for (int i = 0; i < 4; ++i)
        #pragma unroll
        for (int j = 0; j < 4; ++j)
            Pb[(size_t)(o0 + og * 4 + i) * 256 + j * 64 + cb] = f2bf(pacc[i][j]);
}

// ---------------- K5: out = P x + cvec (R11 best). 128-n tile, 64 KB LDS, single
// barrier; all 64 x-loads upfront; P-fragment 1-step prefetch; operand-swapped
// MFMA; float4 stores.
__global__ __launch_bounds__(512) void out_gemm(
        const unsigned short* __restrict__ P, const float* __restrict__ x,
        const float* __restrict__ cvec, float* __restrict__ out) {
    const int n0 = blockIdx.x * 128;
    const int b  = blockIdx.y;
    __shared__ __align__(16) unsigned short Bs[8 * 128 * 32];  // 64 KB: [s][n][32k] swizzled
    const int tid = threadIdx.x, lane = tid & 63, w = tid >> 6;
    const int wr = w >> 1, wc = w & 1;          // 4x64(m) x 2x64(n) wave grid
    const int l15 = lane & 15, lg = lane >> 4;
    const unsigned short* Pb = P + (size_t)b * 65536;

    // ---- stage: issue ALL loads, then convert+store (single latency exposure)
    {
        const int sn = tid & 127;                  // n row
        const int sg = tid >> 7;                   // k-slot 0..3 (8 k each)
        const float* xcol = x + (size_t)b * 256 * HW + n0 + sn;
        float bv[64];
        #pragma unroll
        for (int s = 0; s < 8; ++s)
            #pragma unroll
            for (int i = 0; i < 8; ++i)
                bv[s * 8 + i] = xcol[(size_t)(s * 32 + sg * 8 + i) * HW];
        const int wslot = ((sg ^ ((sn >> 1) & 3)) << 4);
        #pragma unroll
        for (int s = 0; s < 8; ++s) {
            uint4 Bv;
            uint32_t* Bp = reinterpret_cast<uint32_t*>(&Bv);
            #pragma unroll
            for (int p = 0; p < 4; ++p)
                Bp[p] = pk_bf16(bv[s * 8 + 2 * p], bv[s * 8 + 2 * p + 1]);
            *reinterpret_cast<uint4*>((char*)Bs + s * 8192 + sn * 64 + wslot) = Bv;
        }
    }
    __syncthreads();

    // ---- compute: K=256, P fragments prefetched 1 step ahead (static ping-pong)
    f32x4 acc[4][4] = {};   // [m-frag][n-frag]; lane: m = +l15, n = +lg*4+reg
    const int m4r = (l15 >> 1) & 3;
    bf16x8 fp0[4], fp1[4];
    #pragma unroll
    for (int i = 0; i < 4; ++i)
        fp0[i] = *reinterpret_cast<const bf16x8*>(
            Pb + (size_t)(wr * 64 + i * 16 + l15) * 256 + lg * 8);
    #pragma unroll
    for (int s = 0; s < 8; ++s) {
        bf16x8* cur = (s & 1) ? fp1 : fp0;
        bf16x8* nxt = (s & 1) ? fp0 : fp1;
        if (s < 7) {
            #pragma unroll
            for (int i = 0; i < 4; ++i)
                nxt[i] = *reinterpret_cast<const bf16x8*>(
                    Pb + (size_t)(wr * 64 + i * 16 + l15) * 256 + (s + 1) * 32 + lg * 8);
        }
        #pragma unroll
        for (int j = 0; j < 4; ++j) {
            const int row = wc * 64 + j * 16 + l15;
            const bf16x8 fx = *reinterpret_cast<const bf16x8*>(
                (const char*)Bs + s * 8192 + row * 64 + ((lg ^ m4r) << 4));  // A operand (rows = n)
            #pragma unroll
            for (int i = 0; i < 4; ++i)
                acc[i][j] = __builtin_amdgcn_mfma_f32_16x16x32_bf16(fx, cur[i], acc[i][j], 0, 0, 0);
        }
    }

    float* ob = out + (size_t)b * 256 * HW;
    #pragma unroll
    for (int i = 0; i < 4; ++i) {
        const int m = wr * 64 + i * 16 + l15;
        const float bp = cvec[b * 256 + m];
        #pragma unroll
        for (int j = 0; j < 4; ++j) {
            const int n = n0 + wc * 64 + j * 16 + lg * 4;
            float4 o4;
            o4.x = acc[i][j][0] + bp;
            o4.y = acc[i][j][1] + bp;
            o4.z = acc[i][j][2] + bp;
            o4.w = acc[i][j][3] + bp;
            *reinterpret_cast<float4*>(ob + (size_t)m * HW + n) = o4;
        }
    }
}

extern "C" void kernel_launch(void* const* d_in, const int* in_sizes, int n_in,
                              void* d_out, int out_size, void* d_ws, size_t ws_size,
                              hipStream_t stream) {
    const float* x     = (const float*)d_in[0];
    const float* Wqkv  = (const float*)d_in[1];
    const float* bqkv  = (const float*)d_in[2];
    const float* Wproj = (const float*)d_in[3];
    const float* bproj = (const float*)d_in[4];
    float* out = (float*)d_out;

    // ws layout (bytes):
    //   partG  :        0   67108864   (8*32*256*256 f32)
    //   G      : 67108864    2097152
    //   attn   : 69206016     524288
    //   P      : 69730304    1048576
    //   cvec   : 70778880       8192
    //   partsS : 70787072     262144   -> ~67.7 MiB
    char* ws = (char*)d_ws;
    float* partG   = (float*)(ws);
    float* G       = (float*)(ws + 67108864);
    float* attn    = (float*)(ws + 69206016);
    unsigned short* P = (unsigned short*)(ws + 69730304);
    float* cvec    = (float*)(ws + 70778880);
    float* parts_s = (float*)(ws + 70787072);

    gram    <<<dim3(32, 8),  512, 0, stream>>>(x, partG, parts_s);
    greduce <<<512,          256, 0, stream>>>((const float4*)partG, (float4*)G);
    tlogits <<<128,          256, 0, stream>>>(G, Wqkv, bqkv, parts_s, attn);
    buildMP <<<128,          256, 0, stream>>>(attn, Wproj, Wqkv, bqkv, bproj, P, cvec);
    out_gemm<<<dim3(128, 8), 512, 0, stream>>>(P, x, cvec, out);
}